// Round 1
// baseline (12855.475 us; speedup 1.0000x reference)
//
#include <hip/hip_runtime.h>
#include <stdint.h>
#include <stddef.h>

// ContextSNN: T=50, B=256, IN=1536, H1=H2=4096, OUT=64, fp32, LIF (beta=0.9, thr=1, subtract-reset)
//
// Structure per call:
//   zero_ws                         (m1, m2 = 0)
//   for t in 0..49:
//     gemm_lif<1536,false>          cur1 = x_t @ W1^T (+b1), LIF1 -> s1 (fp32), m1
//     gemm_lif<4096,true>           cur2 = s1  @ W2^T (+b2), LIF2 -> s2 (bit-packed into s2bits[t]), m2
//   gemm3                           part[ks][t*256+b][j] = partial dots of s2bits vs W3 (K split 4)
//   lif3_scan                       sequential LIF3 over t per (b,j), acc -> d_out
//
// ws layout (bytes):
//   [0,4M)    m1   float[256*4096]
//   [4M,8M)   m2   float[256*4096]
//   [8M,12M)  s1   float[256*4096]
//   [12M,20M) s2bits uint32[50*256*128]   (6.55 MB used)
//   [20M,~33M) part float[4*12800*64]     (13.1 MB)

#define T_STEPS 50
#define BATCH   256
#define N_H     4096

__global__ __launch_bounds__(256) void zero_ws(float4* __restrict__ p) {
    // zeros 8 MB = 524288 float4, grid 2048 x 256
    p[(size_t)blockIdx.x * 256 + threadIdx.x] = make_float4(0.f, 0.f, 0.f, 0.f);
}

// Fused GEMM (M=256, N=4096, K template) + LIF epilogue.
// A: [256][K] row-major (binary spikes as fp32). W: [4096][K] row-major.
// Tile 64x64, BK=32, 512 threads, microtile 2x4.
template<int K, bool PACK_BITS>
__global__ __launch_bounds__(512)
void gemm_lif(const float* __restrict__ A, const float* __restrict__ W,
              const float* __restrict__ bias, float* __restrict__ mem,
              float* __restrict__ s_f32, uint32_t* __restrict__ s_bits)
{
    __shared__ float As[32][68];   // [k][row], padded
    __shared__ float Ws[32][68];   // [k][col]
    __shared__ uint8_t us[64][64]; // spike bytes for bit-packing (L2 only)

    const int tid   = threadIdx.x;
    const int abase = blockIdx.y * 64;   // batch-row base (0,64,128,192)
    const int cbase = blockIdx.x * 64;   // neuron-col base

    const int tx = tid & 15;     // 16 col-groups of 4
    const int ty = tid >> 4;     // 32 row-groups of 2

    float acc[2][4];
#pragma unroll
    for (int i = 0; i < 2; ++i)
#pragma unroll
        for (int j = 0; j < 4; ++j) acc[i][j] = 0.f;

    const int lrow = tid >> 3;   // 0..63 staging row
    const int lg   = tid & 7;    // 0..7  k-group (x4 floats)

    for (int k0 = 0; k0 < K; k0 += 32) {
        const float4 av = *(const float4*)&A[(size_t)(abase + lrow) * K + k0 + lg * 4];
        const float4 wv = *(const float4*)&W[(size_t)(cbase + lrow) * K + k0 + lg * 4];
        __syncthreads();  // previous iteration's compute must be done
        As[lg * 4 + 0][lrow] = av.x;
        As[lg * 4 + 1][lrow] = av.y;
        As[lg * 4 + 2][lrow] = av.z;
        As[lg * 4 + 3][lrow] = av.w;
        Ws[lg * 4 + 0][lrow] = wv.x;
        Ws[lg * 4 + 1][lrow] = wv.y;
        Ws[lg * 4 + 2][lrow] = wv.z;
        Ws[lg * 4 + 3][lrow] = wv.w;
        __syncthreads();
#pragma unroll
        for (int kk = 0; kk < 32; ++kk) {
            const float2 a2 = *(const float2*)&As[kk][ty * 2];
            const float4 b4 = *(const float4*)&Ws[kk][tx * 4];
            acc[0][0] += a2.x * b4.x;
            acc[0][1] += a2.x * b4.y;
            acc[0][2] += a2.x * b4.z;
            acc[0][3] += a2.x * b4.w;
            acc[1][0] += a2.y * b4.x;
            acc[1][1] += a2.y * b4.y;
            acc[1][2] += a2.y * b4.z;
            acc[1][3] += a2.y * b4.w;
        }
    }

    // LIF epilogue: mem_new = beta*mem + cur - (mem_prev>thr), spike = mem_new>thr
    const int r0    = abase + ty * 2;
    const int c0loc = tx * 4;
    const int c0    = cbase + c0loc;
    const float4 bv = *(const float4*)&bias[c0];

#pragma unroll
    for (int i = 0; i < 2; ++i) {
        const size_t off = (size_t)(r0 + i) * N_H + c0;
        const float4 mp = *(const float4*)&mem[off];
        float4 mn, sp;
        {
            float cur = acc[i][0] + bv.x;
            mn.x = 0.9f * mp.x + cur - ((mp.x > 1.0f) ? 1.0f : 0.0f);
            sp.x = (mn.x > 1.0f) ? 1.0f : 0.0f;
        }
        {
            float cur = acc[i][1] + bv.y;
            mn.y = 0.9f * mp.y + cur - ((mp.y > 1.0f) ? 1.0f : 0.0f);
            sp.y = (mn.y > 1.0f) ? 1.0f : 0.0f;
        }
        {
            float cur = acc[i][2] + bv.z;
            mn.z = 0.9f * mp.z + cur - ((mp.z > 1.0f) ? 1.0f : 0.0f);
            sp.z = (mn.z > 1.0f) ? 1.0f : 0.0f;
        }
        {
            float cur = acc[i][3] + bv.w;
            mn.w = 0.9f * mp.w + cur - ((mp.w > 1.0f) ? 1.0f : 0.0f);
            sp.w = (mn.w > 1.0f) ? 1.0f : 0.0f;
        }
        *(float4*)&mem[off] = mn;
        if constexpr (!PACK_BITS) {
            *(float4*)&s_f32[off] = sp;
        } else {
            us[ty * 2 + i][c0loc + 0] = (uint8_t)sp.x;
            us[ty * 2 + i][c0loc + 1] = (uint8_t)sp.y;
            us[ty * 2 + i][c0loc + 2] = (uint8_t)sp.z;
            us[ty * 2 + i][c0loc + 3] = (uint8_t)sp.w;
        }
    }

    if constexpr (PACK_BITS) {
        __syncthreads();
        if (tid < 128) {
            const int r = tid >> 1;     // local row 0..63
            const int w = tid & 1;      // which 32-col word
            uint32_t bits = 0;
#pragma unroll
            for (int b = 0; b < 32; ++b)
                bits |= ((uint32_t)us[r][w * 32 + b]) << b;
            s_bits[(size_t)(abase + r) * 128 + (cbase >> 5) + w] = bits;
        }
    }
}

// Batched layer-3 GEMM over all timesteps: M'=50*256=12800 rows, N=64, K=4096 split 4.
// A from packed bits, W3 [64][4096] row-major. Tile 64x64, BK=32, 256 threads, microtile 4x4.
__global__ __launch_bounds__(256)
void gemm3(const uint32_t* __restrict__ s_bits, const float* __restrict__ W3,
           float* __restrict__ part)
{
    __shared__ float As[32][68];
    __shared__ float Ws[32][68];

    const int tid     = threadIdx.x;
    const int rowbase = blockIdx.x * 64;  // 0..199
    const int ks      = blockIdx.y;       // K-split 0..3

    const int tx = tid & 15;
    const int ty = tid >> 4;   // 0..15

    float acc[4][4];
#pragma unroll
    for (int i = 0; i < 4; ++i)
#pragma unroll
        for (int j = 0; j < 4; ++j) acc[i][j] = 0.f;

    const int r  = tid & 63;   // bits staging row
    const int q  = tid >> 6;   // 0..3 (8 bits each)
    const int wr = tid >> 3;   // W staging row 0..31 (+32 second pass)
    const int wg = tid & 7;

    for (int c = 0; c < 32; ++c) {
        const int k0 = ks * 1024 + c * 32;
        const uint32_t word = s_bits[(size_t)(rowbase + r) * 128 + (k0 >> 5)];
        const float4 wv0 = *(const float4*)&W3[(size_t)wr * 4096 + k0 + wg * 4];
        const float4 wv1 = *(const float4*)&W3[(size_t)(wr + 32) * 4096 + k0 + wg * 4];
        __syncthreads();
#pragma unroll
        for (int u = 0; u < 8; ++u)
            As[q * 8 + u][r] = (float)((word >> (q * 8 + u)) & 1u);
        Ws[wg * 4 + 0][wr] = wv0.x;
        Ws[wg * 4 + 1][wr] = wv0.y;
        Ws[wg * 4 + 2][wr] = wv0.z;
        Ws[wg * 4 + 3][wr] = wv0.w;
        Ws[wg * 4 + 0][wr + 32] = wv1.x;
        Ws[wg * 4 + 1][wr + 32] = wv1.y;
        Ws[wg * 4 + 2][wr + 32] = wv1.z;
        Ws[wg * 4 + 3][wr + 32] = wv1.w;
        __syncthreads();
#pragma unroll
        for (int kk = 0; kk < 32; ++kk) {
            const float4 a4 = *(const float4*)&As[kk][ty * 4];
            const float4 b4 = *(const float4*)&Ws[kk][tx * 4];
            acc[0][0] += a4.x * b4.x; acc[0][1] += a4.x * b4.y;
            acc[0][2] += a4.x * b4.z; acc[0][3] += a4.x * b4.w;
            acc[1][0] += a4.y * b4.x; acc[1][1] += a4.y * b4.y;
            acc[1][2] += a4.y * b4.z; acc[1][3] += a4.y * b4.w;
            acc[2][0] += a4.z * b4.x; acc[2][1] += a4.z * b4.y;
            acc[2][2] += a4.z * b4.z; acc[2][3] += a4.z * b4.w;
            acc[3][0] += a4.w * b4.x; acc[3][1] += a4.w * b4.y;
            acc[3][2] += a4.w * b4.z; acc[3][3] += a4.w * b4.w;
        }
    }

#pragma unroll
    for (int i = 0; i < 4; ++i) {
        float4 v = make_float4(acc[i][0], acc[i][1], acc[i][2], acc[i][3]);
        *(float4*)&part[((size_t)ks * 12800 + rowbase + ty * 4 + i) * 64 + tx * 4] = v;
    }
}

// Sequential LIF3 over t for each (b, j); sums the 4 K-split partials + bias.
__global__ __launch_bounds__(256)
void lif3_scan(const float* __restrict__ part, const float* __restrict__ b3,
               float* __restrict__ out)
{
    const int g = blockIdx.x * 256 + threadIdx.x;  // 0..16383
    const int j = g & 63;
    const int b = g >> 6;
    const float bj = b3[j];
    float m = 0.f, accum = 0.f;
    for (int t = 0; t < T_STEPS; ++t) {
        const size_t row = (size_t)t * 256 + b;
        float cur = part[row * 64 + j]
                  + part[((size_t)12800 + row) * 64 + j]
                  + part[((size_t)2 * 12800 + row) * 64 + j]
                  + part[((size_t)3 * 12800 + row) * 64 + j] + bj;
        const float reset = (m > 1.0f) ? 1.0f : 0.0f;
        m = 0.9f * m + cur - reset;
        accum += (m > 1.0f) ? 1.0f : 0.0f;
    }
    out[g] = accum;
}

extern "C" void kernel_launch(void* const* d_in, const int* in_sizes, int n_in,
                              void* d_out, int out_size, void* d_ws, size_t ws_size,
                              hipStream_t stream)
{
    const float* x  = (const float*)d_in[0];
    const float* W1 = (const float*)d_in[1];
    const float* b1 = (const float*)d_in[2];
    const float* W2 = (const float*)d_in[3];
    const float* b2 = (const float*)d_in[4];
    const float* W3 = (const float*)d_in[5];
    const float* b3 = (const float*)d_in[6];

    char* ws = (char*)d_ws;
    float*    m1     = (float*)(ws);
    float*    m2     = (float*)(ws + (size_t)4 * 1024 * 1024);
    float*    s1     = (float*)(ws + (size_t)8 * 1024 * 1024);
    uint32_t* s2bits = (uint32_t*)(ws + (size_t)12 * 1024 * 1024);
    float*    part   = (float*)(ws + (size_t)20 * 1024 * 1024);

    // zero m1 + m2 (contiguous 8 MB)
    zero_ws<<<2048, 256, 0, stream>>>((float4*)m1);

    for (int t = 0; t < T_STEPS; ++t) {
        gemm_lif<1536, false><<<dim3(64, 4), 512, 0, stream>>>(
            x + (size_t)t * BATCH * 1536, W1, b1, m1, s1, nullptr);
        gemm_lif<4096, true><<<dim3(64, 4), 512, 0, stream>>>(
            s1, W2, b2, m2, nullptr, s2bits + (size_t)t * BATCH * 128);
    }

    gemm3<<<dim3(200, 4), 256, 0, stream>>>(s2bits, W3, part);
    lif3_scan<<<64, 256, 0, stream>>>(part, b3, (float*)d_out);
}

// Round 3
// 4232.498 us; speedup vs baseline: 3.0373x; 3.0373x over previous
//
#include <hip/hip_runtime.h>
#include <stdint.h>
#include <stddef.h>

// ContextSNN round 3: bf16 MFMA GEMMs with exact 3-plane weight split.
// T=50, B=256, IN=1536, H1=H2=4096, OUT=64. LIF beta=0.9, thr=1, subtract-reset.
//
// New path (needs ~218 MB ws):
//   prep: split W1,W2 into 3 exact truncated-bf16 planes; convert x to bf16; zero m1,m2
//   per t: gemm_mfma(K=1536, A=x_t)   -> part[8][256][4096]   (split-K 8, 3 planes)
//          reduce_lif<0>              -> s1 (bf16 spikes), m1
//          gemm_mfma(K=4096, A=s1)    -> part
//          reduce_lif<1>              -> s2bits (ballot-packed), m2
//   gemm3 (binary x W3, all t batched) + lif3_scan -> out
// Fallback path (= round-1 fp32, needs 33 MB) if ws_size is too small.

#define T_STEPS 50
#define BATCH   256
#define N_H     4096

typedef unsigned short u16;
typedef __attribute__((ext_vector_type(4))) unsigned short u16x4;
typedef __attribute__((ext_vector_type(8))) short bfrag8;   // 8 bf16 = 4 VGPRs
typedef __attribute__((ext_vector_type(4))) float f32x4;

#define GLL16(gp, lp) __builtin_amdgcn_global_load_lds( \
    (const __attribute__((address_space(1))) void*)(gp), \
    (__attribute__((address_space(3))) void*)(lp), 16, 0, 0)

// ---------------------------------------------------------------------------
// prep kernels
// ---------------------------------------------------------------------------

__global__ __launch_bounds__(256) void zero_ws(float4* __restrict__ p) {
    p[(size_t)blockIdx.x * 256 + threadIdx.x] = make_float4(0.f, 0.f, 0.f, 0.f);
}

struct Split3 { u16 h, m, l; };

__device__ inline Split3 split1(float w) {
    Split3 r;
    unsigned uh = __float_as_uint(w);
    r.h = (u16)(uh >> 16);
    float rh = w - __uint_as_float(uh & 0xFFFF0000u);      // exact (Sterbenz)
    unsigned um = __float_as_uint(rh);
    r.m = (u16)(um >> 16);
    float rm = rh - __uint_as_float(um & 0xFFFF0000u);     // exact, <=8 sig bits left
    r.l = (u16)(__float_as_uint(rm) >> 16);                // exact
    return r;
}

// W fp32 [nelem] -> P[3][nelem] truncated-bf16 planes (exact sum)
__global__ __launch_bounds__(256)
void split3(const float4* __restrict__ W, u16* __restrict__ P, size_t plane_elems) {
    const size_t i = (size_t)blockIdx.x * 256 + threadIdx.x;   // float4 index
    const float4 w = W[i];
    const Split3 sx = split1(w.x);
    const Split3 sy = split1(w.y);
    const Split3 sz = split1(w.z);
    const Split3 sw = split1(w.w);
    u16x4 h, m, l;
    h[0] = sx.h; h[1] = sy.h; h[2] = sz.h; h[3] = sw.h;
    m[0] = sx.m; m[1] = sy.m; m[2] = sz.m; m[3] = sw.m;
    l[0] = sx.l; l[1] = sy.l; l[2] = sz.l; l[3] = sw.l;
    *(u16x4*)&P[4 * i]                   = h;
    *(u16x4*)&P[plane_elems + 4 * i]     = m;
    *(u16x4*)&P[2 * plane_elems + 4 * i] = l;
}

// fp32 (binary values) -> bf16 (exact)
__global__ __launch_bounds__(256)
void xcvt(const float4* __restrict__ in, u16x4* __restrict__ out) {
    const size_t i = (size_t)blockIdx.x * 256 + threadIdx.x;
    const float4 v = in[i];
    u16x4 o;
    o[0] = (u16)(__float_as_uint(v.x) >> 16);
    o[1] = (u16)(__float_as_uint(v.y) >> 16);
    o[2] = (u16)(__float_as_uint(v.z) >> 16);
    o[3] = (u16)(__float_as_uint(v.w) >> 16);
    out[i] = o;
}

// ---------------------------------------------------------------------------
// MFMA GEMM: C_partial = A[256][K] @ Wp[3][4096][K]^T over this block's flat-K
// slice. Block tile 128x128, 4 waves of 64x64, BK=32, split-K = 8 over the
// flattened (plane,k) range of length 3K.
// ---------------------------------------------------------------------------
template<int K, int FPB>   // FPB = 3*K/8, flat-K per block
__global__ __launch_bounds__(256, 2)
void gemm_mfma(const u16* __restrict__ A, const u16* __restrict__ Wp,
               float* __restrict__ part)
{
    __shared__ u16 As[128 * 32];   // [row][k], 64 B row stride
    __shared__ u16 Bs[128 * 32];

    const int tid  = threadIdx.x;
    const int wave = tid >> 6, lane = tid & 63;
    const int wm = wave >> 1, wn = wave & 1;

    const int cbase = blockIdx.x * 128;   // neuron cols
    const int abase = blockIdx.y * 128;   // batch rows
    const int ks    = blockIdx.z;

    // flat (plane,k) start for this block
    int p = 0, k = ks * FPB;
    while (k >= K) { k -= K; ++p; }

    f32x4 acc[4][4];
#pragma unroll
    for (int i = 0; i < 4; ++i)
#pragma unroll
        for (int j = 0; j < 4; ++j) acc[i][j] = (f32x4)(0.f);

    // staging: 8 KB per tile = 4 waves x 2 issues x 1 KB (16 B/lane)
    const int soff0 = wave * 2048 + lane * 16;
    const int soff1 = soff0 + 1024;
    const int r0 = soff0 >> 6, kb0 = soff0 & 63;
    const int r1 = soff1 >> 6, kb1 = soff1 & 63;

    const char* Abytes = (const char*)A;
    const char* Wbytes = (const char*)Wp;
    const size_t aoff0 = (size_t)(abase + r0) * K * 2 + kb0;
    const size_t aoff1 = (size_t)(abase + r1) * K * 2 + kb1;
    const size_t boff0 = (size_t)(cbase + r0) * K * 2 + kb0;
    const size_t boff1 = (size_t)(cbase + r1) * K * 2 + kb1;
    const size_t planeB = (size_t)N_H * K * 2;

    char* ldsA0 = (char*)As + wave * 2048;
    char* ldsA1 = ldsA0 + 1024;
    char* ldsB0 = (char*)Bs + wave * 2048;
    char* ldsB1 = ldsB0 + 1024;

    const int rlo = lane & 15, rhi = lane >> 4;
    const char* pAf = (char*)As + (wm * 64 + rlo) * 64 + rhi * 16;
    const char* pBf = (char*)Bs + (wn * 64 + rlo) * 64 + rhi * 16;

    for (int f = 0; f < FPB; f += 32) {
        const char* ak = Abytes + (size_t)k * 2;
        const char* bk = Wbytes + (size_t)p * planeB + (size_t)k * 2;
        __syncthreads();                 // LDS free (prior reads done)
        GLL16(ak + aoff0, ldsA0);
        GLL16(ak + aoff1, ldsA1);
        GLL16(bk + boff0, ldsB0);
        GLL16(bk + boff1, ldsB1);
        __syncthreads();                 // drains vmcnt before barrier

        bfrag8 av[4], bv[4];
#pragma unroll
        for (int i = 0; i < 4; ++i) av[i] = *(const bfrag8*)(pAf + i * 1024);
#pragma unroll
        for (int j = 0; j < 4; ++j) bv[j] = *(const bfrag8*)(pBf + j * 1024);
#pragma unroll
        for (int i = 0; i < 4; ++i)
#pragma unroll
            for (int j = 0; j < 4; ++j)
                acc[i][j] = __builtin_amdgcn_mfma_f32_16x16x32_bf16(
                    av[i], bv[j], acc[i][j], 0, 0, 0);

        k += 32;
        if (k >= K) { k = 0; ++p; }
    }

    // write 128x128 fp32 partial: D row=(lane>>4)*4+r, col=lane&15 per 16x16 tile
    float* pout = part + (size_t)ks * (BATCH * N_H);
    const int orow = abase + wm * 64 + rhi * 4;
    const int ocol = cbase + wn * 64 + rlo;
#pragma unroll
    for (int i = 0; i < 4; ++i)
#pragma unroll
        for (int j = 0; j < 4; ++j)
#pragma unroll
            for (int r = 0; r < 4; ++r)
                pout[(size_t)(orow + i * 16 + r) * N_H + ocol + j * 16] = acc[i][j][r];
}

// ---------------------------------------------------------------------------
// reduce 8 split-K partials + bias, LIF update. MODE 0: store bf16 spikes (s1).
// MODE 1: ballot-pack spike bits (s2bits). One thread per (row, col).
// ---------------------------------------------------------------------------
template<int MODE>
__global__ __launch_bounds__(256)
void reduce_lif(const float* __restrict__ part, const float* __restrict__ bias,
                float* __restrict__ mem, u16* __restrict__ s1,
                uint32_t* __restrict__ sbits)
{
    const int idx = blockIdx.x * 256 + threadIdx.x;   // 0 .. 1048575
    const int col = idx & (N_H - 1);
    float cur = bias[col];
#pragma unroll
    for (int s = 0; s < 8; ++s) cur += part[(size_t)s * (BATCH * N_H) + idx];
    const float mp = mem[idx];
    const float mn = 0.9f * mp + cur - ((mp > 1.0f) ? 1.0f : 0.0f);
    mem[idx] = mn;
    const bool sp = mn > 1.0f;
    if constexpr (MODE == 0) {
        s1[idx] = sp ? (u16)0x3F80 : (u16)0;    // bf16 1.0 / 0.0
    } else {
        const unsigned long long m = __ballot(sp ? 1 : 0);
        const int lane = threadIdx.x & 63;
        if ((lane & 31) == 0)
            sbits[idx >> 5] = (uint32_t)(m >> (lane & 32));
    }
}

// ---------------------------------------------------------------------------
// layer 3 (unchanged): batched binary GEMM over packed bits + scan
// ---------------------------------------------------------------------------
__global__ __launch_bounds__(256)
void gemm3(const uint32_t* __restrict__ s_bits, const float* __restrict__ W3,
           float* __restrict__ part)
{
    __shared__ float As[32][68];
    __shared__ float Ws[32][68];

    const int tid = threadIdx.x;
    const int rowbase = blockIdx.x * 64;
    const int ks = blockIdx.y;
    const int tx = tid & 15;
    const int ty = tid >> 4;

    float acc[4][4];
#pragma unroll
    for (int i = 0; i < 4; ++i)
#pragma unroll
        for (int j = 0; j < 4; ++j) acc[i][j] = 0.f;

    const int r  = tid & 63;
    const int q  = tid >> 6;
    const int wr = tid >> 3;
    const int wg = tid & 7;

    for (int c = 0; c < 32; ++c) {
        const int k0 = ks * 1024 + c * 32;
        const uint32_t word = s_bits[(size_t)(rowbase + r) * 128 + (k0 >> 5)];
        const float4 wv0 = *(const float4*)&W3[(size_t)wr * 4096 + k0 + wg * 4];
        const float4 wv1 = *(const float4*)&W3[(size_t)(wr + 32) * 4096 + k0 + wg * 4];
        __syncthreads();
#pragma unroll
        for (int u = 0; u < 8; ++u)
            As[q * 8 + u][r] = (float)((word >> (q * 8 + u)) & 1u);
        Ws[wg * 4 + 0][wr] = wv0.x;
        Ws[wg * 4 + 1][wr] = wv0.y;
        Ws[wg * 4 + 2][wr] = wv0.z;
        Ws[wg * 4 + 3][wr] = wv0.w;
        Ws[wg * 4 + 0][wr + 32] = wv1.x;
        Ws[wg * 4 + 1][wr + 32] = wv1.y;
        Ws[wg * 4 + 2][wr + 32] = wv1.z;
        Ws[wg * 4 + 3][wr + 32] = wv1.w;
        __syncthreads();
#pragma unroll
        for (int kk = 0; kk < 32; ++kk) {
            const float4 a4 = *(const float4*)&As[kk][ty * 4];
            const float4 b4 = *(const float4*)&Ws[kk][tx * 4];
            acc[0][0] += a4.x * b4.x; acc[0][1] += a4.x * b4.y;
            acc[0][2] += a4.x * b4.z; acc[0][3] += a4.x * b4.w;
            acc[1][0] += a4.y * b4.x; acc[1][1] += a4.y * b4.y;
            acc[1][2] += a4.y * b4.z; acc[1][3] += a4.y * b4.w;
            acc[2][0] += a4.z * b4.x; acc[2][1] += a4.z * b4.y;
            acc[2][2] += a4.z * b4.z; acc[2][3] += a4.z * b4.w;
            acc[3][0] += a4.w * b4.x; acc[3][1] += a4.w * b4.y;
            acc[3][2] += a4.w * b4.z; acc[3][3] += a4.w * b4.w;
        }
    }
#pragma unroll
    for (int i = 0; i < 4; ++i) {
        float4 v = make_float4(acc[i][0], acc[i][1], acc[i][2], acc[i][3]);
        *(float4*)&part[((size_t)ks * 12800 + rowbase + ty * 4 + i) * 64 + tx * 4] = v;
    }
}

__global__ __launch_bounds__(256)
void lif3_scan(const float* __restrict__ part, const float* __restrict__ b3,
               float* __restrict__ out)
{
    const int g = blockIdx.x * 256 + threadIdx.x;
    const int j = g & 63;
    const int b = g >> 6;
    const float bj = b3[j];
    float m = 0.f, accum = 0.f;
    for (int t = 0; t < T_STEPS; ++t) {
        const size_t row = (size_t)t * 256 + b;
        float cur = part[row * 64 + j]
                  + part[((size_t)12800 + row) * 64 + j]
                  + part[((size_t)2 * 12800 + row) * 64 + j]
                  + part[((size_t)3 * 12800 + row) * 64 + j] + bj;
        const float reset = (m > 1.0f) ? 1.0f : 0.0f;
        m = 0.9f * m + cur - reset;
        accum += (m > 1.0f) ? 1.0f : 0.0f;
    }
    out[g] = accum;
}

// ---------------------------------------------------------------------------
// round-1 fp32 fallback GEMM (used only if ws_size is too small for planes)
// ---------------------------------------------------------------------------
template<int K, bool PACK_BITS>
__global__ __launch_bounds__(512)
void gemm_lif(const float* __restrict__ A, const float* __restrict__ W,
              const float* __restrict__ bias, float* __restrict__ mem,
              float* __restrict__ s_f32, uint32_t* __restrict__ s_bits)
{
    __shared__ float As[32][68];
    __shared__ float Ws[32][68];
    __shared__ uint8_t us[64][64];

    const int tid = threadIdx.x;
    const int abase = blockIdx.y * 64;
    const int cbase = blockIdx.x * 64;
    const int tx = tid & 15;
    const int ty = tid >> 4;

    float acc[2][4];
#pragma unroll
    for (int i = 0; i < 2; ++i)
#pragma unroll
        for (int j = 0; j < 4; ++j) acc[i][j] = 0.f;

    const int lrow = tid >> 3;
    const int lg = tid & 7;

    for (int k0 = 0; k0 < K; k0 += 32) {
        const float4 av = *(const float4*)&A[(size_t)(abase + lrow) * K + k0 + lg * 4];
        const float4 wv = *(const float4*)&W[(size_t)(cbase + lrow) * K + k0 + lg * 4];
        __syncthreads();
        As[lg * 4 + 0][lrow] = av.x; As[lg * 4 + 1][lrow] = av.y;
        As[lg * 4 + 2][lrow] = av.z; As[lg * 4 + 3][lrow] = av.w;
        Ws[lg * 4 + 0][lrow] = wv.x; Ws[lg * 4 + 1][lrow] = wv.y;
        Ws[lg * 4 + 2][lrow] = wv.z; Ws[lg * 4 + 3][lrow] = wv.w;
        __syncthreads();
#pragma unroll
        for (int kk = 0; kk < 32; ++kk) {
            const float2 a2 = *(const float2*)&As[kk][ty * 2];
            const float4 b4 = *(const float4*)&Ws[kk][tx * 4];
            acc[0][0] += a2.x * b4.x; acc[0][1] += a2.x * b4.y;
            acc[0][2] += a2.x * b4.z; acc[0][3] += a2.x * b4.w;
            acc[1][0] += a2.y * b4.x; acc[1][1] += a2.y * b4.y;
            acc[1][2] += a2.y * b4.z; acc[1][3] += a2.y * b4.w;
        }
    }

    const int r0 = abase + ty * 2;
    const int c0loc = tx * 4;
    const int c0 = cbase + c0loc;
    const float4 bv = *(const float4*)&bias[c0];

#pragma unroll
    for (int i = 0; i < 2; ++i) {
        const size_t off = (size_t)(r0 + i) * N_H + c0;
        const float4 mp = *(const float4*)&mem[off];
        float4 mn, sp;
        { float cur = acc[i][0] + bv.x;
          mn.x = 0.9f * mp.x + cur - ((mp.x > 1.0f) ? 1.0f : 0.0f);
          sp.x = (mn.x > 1.0f) ? 1.0f : 0.0f; }
        { float cur = acc[i][1] + bv.y;
          mn.y = 0.9f * mp.y + cur - ((mp.y > 1.0f) ? 1.0f : 0.0f);
          sp.y = (mn.y > 1.0f) ? 1.0f : 0.0f; }
        { float cur = acc[i][2] + bv.z;
          mn.z = 0.9f * mp.z + cur - ((mp.z > 1.0f) ? 1.0f : 0.0f);
          sp.z = (mn.z > 1.0f) ? 1.0f : 0.0f; }
        { float cur = acc[i][3] + bv.w;
          mn.w = 0.9f * mp.w + cur - ((mp.w > 1.0f) ? 1.0f : 0.0f);
          sp.w = (mn.w > 1.0f) ? 1.0f : 0.0f; }
        *(float4*)&mem[off] = mn;
        if constexpr (!PACK_BITS) {
            *(float4*)&s_f32[off] = sp;
        } else {
            us[ty * 2 + i][c0loc + 0] = (uint8_t)sp.x;
            us[ty * 2 + i][c0loc + 1] = (uint8_t)sp.y;
            us[ty * 2 + i][c0loc + 2] = (uint8_t)sp.z;
            us[ty * 2 + i][c0loc + 3] = (uint8_t)sp.w;
        }
    }

    if constexpr (PACK_BITS) {
        __syncthreads();
        if (tid < 128) {
            const int r = tid >> 1;
            const int w = tid & 1;
            uint32_t bits = 0;
#pragma unroll
            for (int b = 0; b < 32; ++b)
                bits |= ((uint32_t)us[r][w * 32 + b]) << b;
            s_bits[(size_t)(abase + r) * 128 + (cbase >> 5) + w] = bits;
        }
    }
}

// ---------------------------------------------------------------------------
extern "C" void kernel_launch(void* const* d_in, const int* in_sizes, int n_in,
                              void* d_out, int out_size, void* d_ws, size_t ws_size,
                              hipStream_t stream)
{
    const float* x  = (const float*)d_in[0];
    const float* W1 = (const float*)d_in[1];
    const float* b1 = (const float*)d_in[2];
    const float* W2 = (const float*)d_in[3];
    const float* b2 = (const float*)d_in[4];
    const float* W3 = (const float*)d_in[5];
    const float* b3 = (const float*)d_in[6];

    char* ws = (char*)d_ws;

    // new-path ws layout
    const size_t oW1p  = 0;                       // 37,748,736
    const size_t oW2p  = 37748736;                // 100,663,296
    const size_t oXb   = 138412032;               // 39,321,600
    const size_t oS1   = 177733632;               // 2,097,152
    const size_t oM1   = 179830784;               // 4,194,304
    const size_t oM2   = 184025088;               // 4,194,304 (contiguous with m1)
    const size_t oPart = 188219392;               // 33,554,432 (8 x 4 MB; aliased by part3)
    const size_t oS2b  = 221773824;               // 6,553,600
    const size_t NEED  = 228327424;

    if (ws_size >= NEED) {
        u16*      W1p    = (u16*)(ws + oW1p);
        u16*      W2p    = (u16*)(ws + oW2p);
        u16*      xb     = (u16*)(ws + oXb);
        u16*      s1     = (u16*)(ws + oS1);
        float*    m1     = (float*)(ws + oM1);
        float*    m2     = (float*)(ws + oM2);
        float*    part   = (float*)(ws + oPart);
        uint32_t* s2bits = (uint32_t*)(ws + oS2b);
        float*    part3  = part;   // reused after last reduce_lif

        split3<<<6144, 256, 0, stream>>>((const float4*)W1, W1p, (size_t)4096 * 1536);
        split3<<<16384, 256, 0, stream>>>((const float4*)W2, W2p, (size_t)4096 * 4096);
        xcvt<<<19200, 256, 0, stream>>>((const float4*)x, (u16x4*)xb);
        zero_ws<<<2048, 256, 0, stream>>>((float4*)m1);   // m1 + m2

        for (int t = 0; t < T_STEPS; ++t) {
            gemm_mfma<1536, 576><<<dim3(32, 2, 8), 256, 0, stream>>>(
                xb + (size_t)t * BATCH * 1536, W1p, part);
            reduce_lif<0><<<4096, 256, 0, stream>>>(part, b1, m1, s1, nullptr);
            gemm_mfma<4096, 1536><<<dim3(32, 2, 8), 256, 0, stream>>>(
                s1, W2p, part);
            reduce_lif<1><<<4096, 256, 0, stream>>>(part, b2, m2, nullptr,
                                                    s2bits + (size_t)t * BATCH * 128);
        }
        gemm3<<<dim3(200, 4), 256, 0, stream>>>(s2bits, W3, part3);
        lif3_scan<<<64, 256, 0, stream>>>(part3, b3, (float*)d_out);
    } else {
        // round-1 fp32 fallback (33 MB)
        float*    m1     = (float*)(ws);
        float*    m2     = (float*)(ws + (size_t)4 * 1024 * 1024);
        float*    s1     = (float*)(ws + (size_t)8 * 1024 * 1024);
        uint32_t* s2bits = (uint32_t*)(ws + (size_t)12 * 1024 * 1024);
        float*    part   = (float*)(ws + (size_t)20 * 1024 * 1024);

        zero_ws<<<2048, 256, 0, stream>>>((float4*)m1);
        for (int t = 0; t < T_STEPS; ++t) {
            gemm_lif<1536, false><<<dim3(64, 4), 512, 0, stream>>>(
                x + (size_t)t * BATCH * 1536, W1, b1, m1, s1, nullptr);
            gemm_lif<4096, true><<<dim3(64, 4), 512, 0, stream>>>(
                s1, W2, b2, m2, nullptr, s2bits + (size_t)t * BATCH * 128);
        }
        gemm3<<<dim3(200, 4), 256, 0, stream>>>(s2bits, W3, part);
        lif3_scan<<<64, 256, 0, stream>>>(part, b3, (float*)d_out);
    }
}

// Round 4
// 2880.059 us; speedup vs baseline: 4.4636x; 1.4696x over previous
//
#include <hip/hip_runtime.h>
#include <stdint.h>
#include <stddef.h>
#include <math.h>

// ContextSNN round 4: i8 MFMA GEMMs, 3 balanced base-256 digit planes (24-bit
// fixed point, error ~1e-9 per weight), exact i32 accumulation.
// T=50, B=256, IN=1536, H1=H2=4096, OUT=64. LIF beta=0.9, thr=1, subtract.
//
//   prep: split W1,W2,W3 into 3 i8 digit planes; x -> i8; zero m1,m2
//   per t: gemm_i8<1536>  part[6][256][4096]  (z = plane*2 + K-half, scaled fp32)
//          reduce_lif<0>  -> s1 (i8 spikes), m1
//          gemm_i8<4096>  part[6]
//          reduce_lif<1>  -> s2 i8 row block, m2
//   gemm3_i8 (M=12800, N=64, z=6) -> part3[6][12800][64]
//   lif3_scan<6> -> out
// Fallback = round-1 fp32 path if ws too small.

#define T_STEPS 50
#define BATCH   256
#define N_H     4096
#define DEN     8355711   // 127*65536 + 127*256 + 127

typedef unsigned short u16;
typedef __attribute__((ext_vector_type(4))) int i32x4;

#define GLL16(gp, lp) __builtin_amdgcn_global_load_lds( \
    (const __attribute__((address_space(1))) void*)(gp), \
    (__attribute__((address_space(3))) void*)(lp), 16, 0, 0)

// ---------------------------------------------------------------------------
// prep
// ---------------------------------------------------------------------------
__global__ __launch_bounds__(256) void zero_ws(float4* __restrict__ p) {
    p[(size_t)blockIdx.x * 256 + threadIdx.x] = make_float4(0.f, 0.f, 0.f, 0.f);
}

__device__ inline void digits3(float w, float inv_s, int& h, int& m, int& l) {
    int V = (int)rintf(w * inv_s);
    V = min(max(V, -DEN), DEN);
    l = ((V + 128) & 255) - 128;
    const int V2 = (V - l) >> 8;
    m = ((V2 + 128) & 255) - 128;
    h = (V2 - m) >> 8;                 // in [-128,127] by construction
}

// W fp32 -> 3 i8 digit planes, plane-major [3][plane_elems]
__global__ __launch_bounds__(256)
void split3_i8(const float4* __restrict__ W, char* __restrict__ P,
               size_t plane_elems, float inv_s)
{
    const size_t i = (size_t)blockIdx.x * 256 + threadIdx.x;   // float4 idx
    const float4 w = W[i];
    int h0,m0,l0,h1,m1,l1,h2,m2,l2,h3,m3,l3;
    digits3(w.x, inv_s, h0, m0, l0);
    digits3(w.y, inv_s, h1, m1, l1);
    digits3(w.z, inv_s, h2, m2, l2);
    digits3(w.w, inv_s, h3, m3, l3);
    const uint32_t ph = (uint32_t)(uint8_t)h0 | ((uint32_t)(uint8_t)h1 << 8) |
                        ((uint32_t)(uint8_t)h2 << 16) | ((uint32_t)(uint8_t)h3 << 24);
    const uint32_t pm = (uint32_t)(uint8_t)m0 | ((uint32_t)(uint8_t)m1 << 8) |
                        ((uint32_t)(uint8_t)m2 << 16) | ((uint32_t)(uint8_t)m3 << 24);
    const uint32_t pl = (uint32_t)(uint8_t)l0 | ((uint32_t)(uint8_t)l1 << 8) |
                        ((uint32_t)(uint8_t)l2 << 16) | ((uint32_t)(uint8_t)l3 << 24);
    *(uint32_t*)&P[4 * i]                       = ph;
    *(uint32_t*)&P[plane_elems + 4 * i]         = pm;
    *(uint32_t*)&P[2 * plane_elems + 4 * i]     = pl;
}

// fp32 binary -> i8
__global__ __launch_bounds__(256)
void xcvt_i8(const float4* __restrict__ in, uint32_t* __restrict__ out) {
    const size_t i = (size_t)blockIdx.x * 256 + threadIdx.x;
    const float4 v = in[i];
    out[i] = (uint32_t)(v.x > 0.5f) | ((uint32_t)(v.y > 0.5f) << 8) |
             ((uint32_t)(v.z > 0.5f) << 16) | ((uint32_t)(v.w > 0.5f) << 24);
}

// ---------------------------------------------------------------------------
// i8 MFMA GEMM: A[256][K] x Wp[3][4096][K]^T. Block 128x128, 4 waves 64x64,
// BK=64. z = plane*2 + half: each block covers one K-half of one plane.
// Epilogue scales the exact i32 group sum by s_base * 256^(2-plane) -> fp32.
// ---------------------------------------------------------------------------
template<int K>
__global__ __launch_bounds__(256, 2)
void gemm_i8(const char* __restrict__ A, const char* __restrict__ Wp,
             float* __restrict__ part, float s_base)
{
    __shared__ char As[128 * 64];   // [row][k], 64B rows = one BK slice
    __shared__ char Bs[128 * 64];

    const int tid  = threadIdx.x;
    const int wave = tid >> 6, lane = tid & 63;
    const int wm = wave >> 1, wn = wave & 1;

    const int cbase = blockIdx.x * 128;
    const int abase = blockIdx.y * 128;
    const int z = blockIdx.z;          // 0..5
    const int p = z >> 1;              // digit plane
    const int kstart = (z & 1) * (K / 2);

    i32x4 acc[4][4];
#pragma unroll
    for (int i = 0; i < 4; ++i)
#pragma unroll
        for (int j = 0; j < 4; ++j) acc[i][j] = (i32x4)(0);

    const int soff0 = wave * 2048 + lane * 16;
    const int soff1 = soff0 + 1024;
    const int r0 = soff0 >> 6, kb0 = soff0 & 63;
    const int r1 = soff1 >> 6, kb1 = soff1 & 63;

    const size_t aoff0 = (size_t)(abase + r0) * K + kb0;
    const size_t aoff1 = (size_t)(abase + r1) * K + kb1;
    const size_t boff0 = (size_t)(cbase + r0) * K + kb0;
    const size_t boff1 = (size_t)(cbase + r1) * K + kb1;

    const char* Bp = Wp + (size_t)p * N_H * K;

    char* ldsA0 = As + wave * 2048;
    char* ldsA1 = ldsA0 + 1024;
    char* ldsB0 = Bs + wave * 2048;
    char* ldsB1 = ldsB0 + 1024;

    const int rlo = lane & 15, rhi = lane >> 4;
    const char* pAf = As + (wm * 64 + rlo) * 64 + rhi * 16;
    const char* pBf = Bs + (wn * 64 + rlo) * 64 + rhi * 16;

#pragma unroll 2
    for (int it = 0; it < K / 128; ++it) {
        const int k = kstart + it * 64;
        const char* ak = A + k;
        const char* bk = Bp + k;
        __syncthreads();
        GLL16(ak + aoff0, ldsA0);
        GLL16(ak + aoff1, ldsA1);
        GLL16(bk + boff0, ldsB0);
        GLL16(bk + boff1, ldsB1);
        __syncthreads();

        i32x4 av[4], bv[4];
#pragma unroll
        for (int i = 0; i < 4; ++i) av[i] = *(const i32x4*)(pAf + i * 1024);
#pragma unroll
        for (int j = 0; j < 4; ++j) bv[j] = *(const i32x4*)(pBf + j * 1024);
#pragma unroll
        for (int i = 0; i < 4; ++i)
#pragma unroll
            for (int j = 0; j < 4; ++j)
                acc[i][j] = __builtin_amdgcn_mfma_i32_16x16x64_i8(
                    av[i], bv[j], acc[i][j], 0, 0, 0);
    }

    const float sc = s_base * (float)(65536 >> (8 * p));
    float* pout = part + (size_t)z * (BATCH * N_H);
    const int orow = abase + wm * 64 + rhi * 4;
    const int ocol = cbase + wn * 64 + rlo;
#pragma unroll
    for (int i = 0; i < 4; ++i)
#pragma unroll
        for (int j = 0; j < 4; ++j)
#pragma unroll
            for (int r = 0; r < 4; ++r)
                pout[(size_t)(orow + i * 16 + r) * N_H + ocol + j * 16] =
                    (float)acc[i][j][r] * sc;
}

// ---------------------------------------------------------------------------
// layer-3 i8 GEMM: A = s2 i8 [12800][4096], W3p[3][64][4096]. Block 128x64,
// 4 waves (2 in M x 2 in N/32). z = plane*2 + half (K-half 2048).
// ---------------------------------------------------------------------------
__global__ __launch_bounds__(256, 2)
void gemm3_i8(const char* __restrict__ A, const char* __restrict__ W3p,
              float* __restrict__ part3, float s_base)
{
    __shared__ char As[128 * 64];   // 8KB
    __shared__ char Bs[64 * 64];    // 4KB

    const int tid  = threadIdx.x;
    const int wave = tid >> 6, lane = tid & 63;
    const int wm = wave >> 1, wn = wave & 1;

    const int rowbase = blockIdx.x * 128;
    const int z = blockIdx.y;
    const int p = z >> 1;
    const int kstart = (z & 1) * 2048;

    i32x4 acc[4][2];
#pragma unroll
    for (int i = 0; i < 4; ++i)
#pragma unroll
        for (int j = 0; j < 2; ++j) acc[i][j] = (i32x4)(0);

    const int soff0 = wave * 2048 + lane * 16;
    const int soff1 = soff0 + 1024;
    const int r0 = soff0 >> 6, kb0 = soff0 & 63;
    const int r1 = soff1 >> 6, kb1 = soff1 & 63;
    const int soffB = tid * 16;
    const int rB = soffB >> 6, kbB = soffB & 63;

    const size_t aoff0 = (size_t)(rowbase + r0) * 4096 + kb0;
    const size_t aoff1 = (size_t)(rowbase + r1) * 4096 + kb1;
    const size_t boff  = (size_t)rB * 4096 + kbB;

    const char* Bp = W3p + (size_t)p * 64 * 4096;

    char* ldsA0 = As + wave * 2048;
    char* ldsA1 = ldsA0 + 1024;
    char* ldsB  = Bs + wave * 1024;

    const int rlo = lane & 15, rhi = lane >> 4;
    const char* pAf = As + (wm * 64 + rlo) * 64 + rhi * 16;
    const char* pBf = Bs + (wn * 32 + rlo) * 64 + rhi * 16;

    for (int it = 0; it < 32; ++it) {
        const int k = kstart + it * 64;
        __syncthreads();
        GLL16(A + k + aoff0, ldsA0);
        GLL16(A + k + aoff1, ldsA1);
        GLL16(Bp + k + boff, ldsB);
        __syncthreads();

        i32x4 av[4], bv[2];
#pragma unroll
        for (int i = 0; i < 4; ++i) av[i] = *(const i32x4*)(pAf + i * 1024);
#pragma unroll
        for (int j = 0; j < 2; ++j) bv[j] = *(const i32x4*)(pBf + j * 1024);
#pragma unroll
        for (int i = 0; i < 4; ++i)
#pragma unroll
            for (int j = 0; j < 2; ++j)
                acc[i][j] = __builtin_amdgcn_mfma_i32_16x16x64_i8(
                    av[i], bv[j], acc[i][j], 0, 0, 0);
    }

    const float sc = s_base * (float)(65536 >> (8 * p));
    float* pout = part3 + (size_t)z * (12800 * 64);
    const int orow = rowbase + wm * 64 + rhi * 4;
    const int ocol = wn * 32 + rlo;
#pragma unroll
    for (int i = 0; i < 4; ++i)
#pragma unroll
        for (int j = 0; j < 2; ++j)
#pragma unroll
            for (int r = 0; r < 4; ++r)
                pout[(size_t)(orow + i * 16 + r) * 64 + ocol + j * 16] =
                    (float)acc[i][j][r] * sc;
}

// ---------------------------------------------------------------------------
// reduce 6 scaled partials + bias, LIF. MODE 0: i8 spikes -> s1.
// MODE 1: i8 spikes -> s2 row block.
// ---------------------------------------------------------------------------
template<int MODE>
__global__ __launch_bounds__(256)
void reduce_lif(const float* __restrict__ part, const float* __restrict__ bias,
                float* __restrict__ mem, char* __restrict__ sout)
{
    const int idx = blockIdx.x * 256 + threadIdx.x;   // 0 .. 1048575
    const int col = idx & (N_H - 1);
    float cur = bias[col];
#pragma unroll
    for (int g = 0; g < 6; ++g) cur += part[(size_t)g * (BATCH * N_H) + idx];
    const float mp = mem[idx];
    const float mn = 0.9f * mp + cur - ((mp > 1.0f) ? 1.0f : 0.0f);
    mem[idx] = mn;
    sout[idx] = (mn > 1.0f) ? (char)1 : (char)0;
    (void)MODE;
}

// combine NG group partials (stride 12800*64) + bias, sequential LIF over t
template<int NG>
__global__ __launch_bounds__(256)
void lif3_scan(const float* __restrict__ part, const float* __restrict__ b3,
               float* __restrict__ out)
{
    const int g = blockIdx.x * 256 + threadIdx.x;
    const int j = g & 63;
    const int b = g >> 6;
    const float bj = b3[j];
    float m = 0.f, accum = 0.f;
    for (int t = 0; t < T_STEPS; ++t) {
        const size_t row = (size_t)t * 256 + b;
        float cur = bj;
#pragma unroll
        for (int q = 0; q < NG; ++q)
            cur += part[(size_t)q * (12800 * 64) + row * 64 + j];
        const float reset = (m > 1.0f) ? 1.0f : 0.0f;
        m = 0.9f * m + cur - reset;
        accum += (m > 1.0f) ? 1.0f : 0.0f;
    }
    out[g] = accum;
}

// ---------------------------------------------------------------------------
// fp32 fallback path (round 1) — used only if ws_size too small
// ---------------------------------------------------------------------------
template<int K, bool PACK_BITS>
__global__ __launch_bounds__(512)
void gemm_lif(const float* __restrict__ A, const float* __restrict__ W,
              const float* __restrict__ bias, float* __restrict__ mem,
              float* __restrict__ s_f32, uint32_t* __restrict__ s_bits)
{
    __shared__ float As[32][68];
    __shared__ float Ws[32][68];
    __shared__ uint8_t us[64][64];

    const int tid = threadIdx.x;
    const int abase = blockIdx.y * 64;
    const int cbase = blockIdx.x * 64;
    const int tx = tid & 15;
    const int ty = tid >> 4;

    float acc[2][4];
#pragma unroll
    for (int i = 0; i < 2; ++i)
#pragma unroll
        for (int j = 0; j < 4; ++j) acc[i][j] = 0.f;

    const int lrow = tid >> 3;
    const int lg = tid & 7;

    for (int k0 = 0; k0 < K; k0 += 32) {
        const float4 av = *(const float4*)&A[(size_t)(abase + lrow) * K + k0 + lg * 4];
        const float4 wv = *(const float4*)&W[(size_t)(cbase + lrow) * K + k0 + lg * 4];
        __syncthreads();
        As[lg * 4 + 0][lrow] = av.x; As[lg * 4 + 1][lrow] = av.y;
        As[lg * 4 + 2][lrow] = av.z; As[lg * 4 + 3][lrow] = av.w;
        Ws[lg * 4 + 0][lrow] = wv.x; Ws[lg * 4 + 1][lrow] = wv.y;
        Ws[lg * 4 + 2][lrow] = wv.z; Ws[lg * 4 + 3][lrow] = wv.w;
        __syncthreads();
#pragma unroll
        for (int kk = 0; kk < 32; ++kk) {
            const float2 a2 = *(const float2*)&As[kk][ty * 2];
            const float4 b4 = *(const float4*)&Ws[kk][tx * 4];
            acc[0][0] += a2.x * b4.x; acc[0][1] += a2.x * b4.y;
            acc[0][2] += a2.x * b4.z; acc[0][3] += a2.x * b4.w;
            acc[1][0] += a2.y * b4.x; acc[1][1] += a2.y * b4.y;
            acc[1][2] += a2.y * b4.z; acc[1][3] += a2.y * b4.w;
        }
    }

    const int r0 = abase + ty * 2;
    const int c0loc = tx * 4;
    const int c0 = cbase + c0loc;
    const float4 bv = *(const float4*)&bias[c0];

#pragma unroll
    for (int i = 0; i < 2; ++i) {
        const size_t off = (size_t)(r0 + i) * N_H + c0;
        const float4 mp = *(const float4*)&mem[off];
        float4 mn, sp;
        { float cur = acc[i][0] + bv.x;
          mn.x = 0.9f * mp.x + cur - ((mp.x > 1.0f) ? 1.0f : 0.0f);
          sp.x = (mn.x > 1.0f) ? 1.0f : 0.0f; }
        { float cur = acc[i][1] + bv.y;
          mn.y = 0.9f * mp.y + cur - ((mp.y > 1.0f) ? 1.0f : 0.0f);
          sp.y = (mn.y > 1.0f) ? 1.0f : 0.0f; }
        { float cur = acc[i][2] + bv.z;
          mn.z = 0.9f * mp.z + cur - ((mp.z > 1.0f) ? 1.0f : 0.0f);
          sp.z = (mn.z > 1.0f) ? 1.0f : 0.0f; }
        { float cur = acc[i][3] + bv.w;
          mn.w = 0.9f * mp.w + cur - ((mp.w > 1.0f) ? 1.0f : 0.0f);
          sp.w = (mn.w > 1.0f) ? 1.0f : 0.0f; }
        *(float4*)&mem[off] = mn;
        if constexpr (!PACK_BITS) {
            *(float4*)&s_f32[off] = sp;
        } else {
            us[ty * 2 + i][c0loc + 0] = (uint8_t)sp.x;
            us[ty * 2 + i][c0loc + 1] = (uint8_t)sp.y;
            us[ty * 2 + i][c0loc + 2] = (uint8_t)sp.z;
            us[ty * 2 + i][c0loc + 3] = (uint8_t)sp.w;
        }
    }

    if constexpr (PACK_BITS) {
        __syncthreads();
        if (tid < 128) {
            const int r = tid >> 1;
            const int w = tid & 1;
            uint32_t bits = 0;
#pragma unroll
            for (int b = 0; b < 32; ++b)
                bits |= ((uint32_t)us[r][w * 32 + b]) << b;
            s_bits[(size_t)(abase + r) * 128 + (cbase >> 5) + w] = bits;
        }
    }
}

__global__ __launch_bounds__(256)
void gemm3_bits(const uint32_t* __restrict__ s_bits, const float* __restrict__ W3,
                float* __restrict__ part)
{
    __shared__ float As[32][68];
    __shared__ float Ws[32][68];

    const int tid = threadIdx.x;
    const int rowbase = blockIdx.x * 64;
    const int ks = blockIdx.y;
    const int tx = tid & 15;
    const int ty = tid >> 4;

    float acc[4][4];
#pragma unroll
    for (int i = 0; i < 4; ++i)
#pragma unroll
        for (int j = 0; j < 4; ++j) acc[i][j] = 0.f;

    const int r  = tid & 63;
    const int q  = tid >> 6;
    const int wr = tid >> 3;
    const int wg = tid & 7;

    for (int c = 0; c < 32; ++c) {
        const int k0 = ks * 1024 + c * 32;
        const uint32_t word = s_bits[(size_t)(rowbase + r) * 128 + (k0 >> 5)];
        const float4 wv0 = *(const float4*)&W3[(size_t)wr * 4096 + k0 + wg * 4];
        const float4 wv1 = *(const float4*)&W3[(size_t)(wr + 32) * 4096 + k0 + wg * 4];
        __syncthreads();
#pragma unroll
        for (int u = 0; u < 8; ++u)
            As[q * 8 + u][r] = (float)((word >> (q * 8 + u)) & 1u);
        Ws[wg * 4 + 0][wr] = wv0.x;
        Ws[wg * 4 + 1][wr] = wv0.y;
        Ws[wg * 4 + 2][wr] = wv0.z;
        Ws[wg * 4 + 3][wr] = wv0.w;
        Ws[wg * 4 + 0][wr + 32] = wv1.x;
        Ws[wg * 4 + 1][wr + 32] = wv1.y;
        Ws[wg * 4 + 2][wr + 32] = wv1.z;
        Ws[wg * 4 + 3][wr + 32] = wv1.w;
        __syncthreads();
#pragma unroll
        for (int kk = 0; kk < 32; ++kk) {
            const float4 a4 = *(const float4*)&As[kk][ty * 4];
            const float4 b4 = *(const float4*)&Ws[kk][tx * 4];
            acc[0][0] += a4.x * b4.x; acc[0][1] += a4.x * b4.y;
            acc[0][2] += a4.x * b4.z; acc[0][3] += a4.x * b4.w;
            acc[1][0] += a4.y * b4.x; acc[1][1] += a4.y * b4.y;
            acc[1][2] += a4.y * b4.z; acc[1][3] += a4.y * b4.w;
            acc[2][0] += a4.z * b4.x; acc[2][1] += a4.z * b4.y;
            acc[2][2] += a4.z * b4.z; acc[2][3] += a4.z * b4.w;
            acc[3][0] += a4.w * b4.x; acc[3][1] += a4.w * b4.y;
            acc[3][2] += a4.w * b4.z; acc[3][3] += a4.w * b4.w;
        }
    }
#pragma unroll
    for (int i = 0; i < 4; ++i) {
        float4 v = make_float4(acc[i][0], acc[i][1], acc[i][2], acc[i][3]);
        *(float4*)&part[((size_t)ks * 12800 + rowbase + ty * 4 + i) * 64 + tx * 4] = v;
    }
}

// ---------------------------------------------------------------------------
extern "C" void kernel_launch(void* const* d_in, const int* in_sizes, int n_in,
                              void* d_out, int out_size, void* d_ws, size_t ws_size,
                              hipStream_t stream)
{
    const float* x  = (const float*)d_in[0];
    const float* W1 = (const float*)d_in[1];
    const float* b1 = (const float*)d_in[2];
    const float* W2 = (const float*)d_in[3];
    const float* b2 = (const float*)d_in[4];
    const float* W3 = (const float*)d_in[5];
    const float* b3 = (const float*)d_in[6];

    char* ws = (char*)d_ws;

    // i8-path ws layout
    const size_t oW1p  = 0;              // 18,874,368
    const size_t oW2p  = 18874368;       // 50,331,648
    const size_t oW3p  = 69206016;       //    786,432
    const size_t oXi8  = 69992448;       // 19,660,800
    const size_t oS1   = 89653248;       //  1,048,576
    const size_t oS2   = 90701824;       // 52,428,800
    const size_t oM1   = 143130624;      //  4,194,304
    const size_t oM2   = 147324928;      //  4,194,304
    const size_t oPart = 151519232;      // 25,165,824 (part3 aliases)
    const size_t NEED  = 176685056;

    const double bnd1 = 1.0 / sqrt(1536.0);
    const double bnd2 = 1.0 / 64.0;
    const double bnd3 = 1.0 / 64.0;
    const float inv1 = (float)((double)DEN / bnd1), sb1 = (float)(bnd1 / (double)DEN);
    const float inv2 = (float)((double)DEN / bnd2), sb2 = (float)(bnd2 / (double)DEN);
    const float inv3 = (float)((double)DEN / bnd3), sb3 = (float)(bnd3 / (double)DEN);

    if (ws_size >= NEED) {
        char*  W1p  = ws + oW1p;
        char*  W2p  = ws + oW2p;
        char*  W3p  = ws + oW3p;
        char*  xi8  = ws + oXi8;
        char*  s1   = ws + oS1;
        char*  s2   = ws + oS2;
        float* m1   = (float*)(ws + oM1);
        float* part = (float*)(ws + oPart);
        float* part3 = part;

        split3_i8<<<6144, 256, 0, stream>>>((const float4*)W1, W1p,
                                            (size_t)4096 * 1536, inv1);
        split3_i8<<<16384, 256, 0, stream>>>((const float4*)W2, W2p,
                                             (size_t)4096 * 4096, inv2);
        split3_i8<<<256, 256, 0, stream>>>((const float4*)W3, W3p,
                                           (size_t)64 * 4096, inv3);
        xcvt_i8<<<19200, 256, 0, stream>>>((const float4*)x, (uint32_t*)xi8);
        zero_ws<<<2048, 256, 0, stream>>>((float4*)m1);   // m1 + m2

        for (int t = 0; t < T_STEPS; ++t) {
            gemm_i8<1536><<<dim3(32, 2, 6), 256, 0, stream>>>(
                xi8 + (size_t)t * BATCH * 1536, W1p, part, sb1);
            reduce_lif<0><<<4096, 256, 0, stream>>>(part, b1, m1, s1);
            gemm_i8<4096><<<dim3(32, 2, 6), 256, 0, stream>>>(
                s1, W2p, part, sb2);
            reduce_lif<1><<<4096, 256, 0, stream>>>(part, b2,
                (float*)(ws + oM2), s2 + (size_t)t * BATCH * N_H);
        }
        gemm3_i8<<<dim3(100, 6), 256, 0, stream>>>(s2, W3p, part3, sb3);
        lif3_scan<6><<<64, 256, 0, stream>>>(part3, b3, (float*)d_out);
    } else {
        // fp32 fallback (33 MB)
        float*    m1     = (float*)(ws);
        float*    m2     = (float*)(ws + (size_t)4 * 1024 * 1024);
        float*    s1     = (float*)(ws + (size_t)8 * 1024 * 1024);
        uint32_t* s2bits = (uint32_t*)(ws + (size_t)12 * 1024 * 1024);
        float*    part   = (float*)(ws + (size_t)20 * 1024 * 1024);

        zero_ws<<<2048, 256, 0, stream>>>((float4*)m1);
        for (int t = 0; t < T_STEPS; ++t) {
            gemm_lif<1536, false><<<dim3(64, 4), 512, 0, stream>>>(
                x + (size_t)t * BATCH * 1536, W1, b1, m1, s1, nullptr);
            gemm_lif<4096, true><<<dim3(64, 4), 512, 0, stream>>>(
                s1, W2, b2, m2, nullptr, s2bits + (size_t)t * BATCH * 128);
        }
        gemm3_bits<<<dim3(200, 4), 256, 0, stream>>>(s2bits, W3, part);
        lif3_scan<4><<<64, 256, 0, stream>>>(part, b3, (float*)d_out);
    }
}